// Round 1
// baseline (2774.857 us; speedup 1.0000x reference)
//
#include <hip/hip_runtime.h>
#include <hip/hip_bf16.h>
#include <math.h>

// ---------------- problem constants ----------------
#define DD   1024
#define HHN  16
#define DHD  64
#define DFFN 4096
#define VV   32000
#define BBN  2
#define TTN  512
#define SSN  1024      // 2T
#define NRN  2048      // B*S

typedef __attribute__((ext_vector_type(8))) short short8;
typedef __attribute__((ext_vector_type(4))) float f32x4;

__device__ __forceinline__ unsigned short f2bf(float f) {
    __hip_bfloat16 h = __float2bfloat16(f);
    return __builtin_bit_cast(unsigned short, h);
}
__device__ __forceinline__ float bf2f(unsigned short u) {
    return __bfloat162float(__builtin_bit_cast(__hip_bfloat16, u));
}

__device__ __forceinline__ float blockReduceSum(float v) {
    __shared__ float sh[4];
    #pragma unroll
    for (int o = 1; o < 64; o <<= 1) v += __shfl_xor(v, o, 64);
    int lane = threadIdx.x & 63, wv = threadIdx.x >> 6;
    __syncthreads();
    if (lane == 0) sh[wv] = v;
    __syncthreads();
    return sh[0] + sh[1] + sh[2] + sh[3];
}
__device__ __forceinline__ float blockReduceMax(float v) {
    __shared__ float sh[4];
    #pragma unroll
    for (int o = 1; o < 64; o <<= 1) v = fmaxf(v, __shfl_xor(v, o, 64));
    int lane = threadIdx.x & 63, wv = threadIdx.x >> 6;
    __syncthreads();
    if (lane == 0) sh[wv] = v;
    __syncthreads();
    return fmaxf(fmaxf(sh[0], sh[1]), fmaxf(sh[2], sh[3]));
}

// ---------------- embedding ----------------
__global__ __launch_bounds__(256) void embed_k(const int* __restrict__ tok,
                                               const float* __restrict__ temb,
                                               const float* __restrict__ pemb,
                                               const float* __restrict__ mtok,
                                               float* __restrict__ x) {
    int row = blockIdx.x;               // 0..2047
    int b = row >> 10, s = row & 1023;
    int d = threadIdx.x * 4;
    const float* src;
    const float* pe;
    if (s < TTN) {
        int id = tok[b * TTN + s];
        src = temb + (size_t)id * DD + d;
        pe  = pemb + (size_t)s * DD + d;
    } else {
        int sm = s - TTN;
        src = mtok + (size_t)(sm & 15) * DD + d;
        pe  = pemb + (size_t)sm * DD + d;
    }
    float4 v = *(const float4*)src;
    float4 p = *(const float4*)pe;
    v.x += p.x; v.y += p.y; v.z += p.z; v.w += p.w;
    *(float4*)(x + (size_t)row * DD + d) = v;
}

// ---------------- layernorm (f32 in -> bf16 out) ----------------
__global__ __launch_bounds__(256) void ln_k(const float* __restrict__ x,
                                            const float* __restrict__ g,
                                            const float* __restrict__ b,
                                            unsigned short* __restrict__ out) {
    int row = blockIdx.x;
    int d = threadIdx.x * 4;
    const float4 v = *(const float4*)(x + (size_t)row * DD + d);
    float s  = v.x + v.y + v.z + v.w;
    float ss = v.x * v.x + v.y * v.y + v.z * v.z + v.w * v.w;
    s  = blockReduceSum(s);
    ss = blockReduceSum(ss);
    float mu  = s * (1.0f / DD);
    float var = ss * (1.0f / DD) - mu * mu;
    float inv = rsqrtf(var + 1e-5f);
    const float4 gg = *(const float4*)(g + d);
    const float4 bb = *(const float4*)(b + d);
    ushort4 o;
    o.x = f2bf((v.x - mu) * inv * gg.x + bb.x);
    o.y = f2bf((v.y - mu) * inv * gg.y + bb.y);
    o.z = f2bf((v.z - mu) * inv * gg.z + bb.z);
    o.w = f2bf((v.w - mu) * inv * gg.w + bb.w);
    *(ushort4*)(out + (size_t)row * DD + d) = o;
}

// -------- transpose-convert weight: f32 [K,N] -> bf16 [N,K] --------
__global__ void convT_k(const float* __restrict__ w, unsigned short* __restrict__ wt,
                        int K, int N) {
    __shared__ float tile[32][33];
    int n0 = blockIdx.x * 32, k0 = blockIdx.y * 32;
    int tx = threadIdx.x, ty = threadIdx.y;  // (32,8)
    #pragma unroll
    for (int j = 0; j < 4; j++)
        tile[ty + j * 8][tx] = w[(size_t)(k0 + ty + j * 8) * N + n0 + tx];
    __syncthreads();
    #pragma unroll
    for (int j = 0; j < 4; j++)
        wt[(size_t)(n0 + ty + j * 8) * K + k0 + tx] = f2bf(tile[tx][ty + j * 8]);
}

// -------- straight convert f32 -> bf16 --------
__global__ __launch_bounds__(256) void conv_k(const float* __restrict__ w,
                                              unsigned short* __restrict__ o, long n) {
    long i = ((long)blockIdx.x * 256 + threadIdx.x) * 8;
    if (i >= n) return;
    float4 a = *(const float4*)(w + i);
    float4 b = *(const float4*)(w + i + 4);
    __align__(16) unsigned short tmp[8];
    tmp[0] = f2bf(a.x); tmp[1] = f2bf(a.y); tmp[2] = f2bf(a.z); tmp[3] = f2bf(a.w);
    tmp[4] = f2bf(b.x); tmp[5] = f2bf(b.y); tmp[6] = f2bf(b.z); tmp[7] = f2bf(b.w);
    *(int4*)(o + i) = *(const int4*)tmp;
}

// -------- V^T: qkvb v-part [s, h*64+d] -> vt [bh][d][s] --------
__global__ __launch_bounds__(256) void vtr_k(const unsigned short* __restrict__ qkvb,
                                             unsigned short* __restrict__ vt) {
    __shared__ __align__(16) unsigned short tile[64][72];
    int bh = blockIdx.x, st = blockIdx.y;
    int b = bh >> 4, h = bh & 15;
    int t = threadIdx.x;
    int sl = t >> 2, d0 = (t & 3) << 4;
    const unsigned short* src =
        qkvb + (size_t)(b * SSN + st * 64 + sl) * (3 * DD) + 2 * DD + h * 64 + d0;
    *(int4*)&tile[sl][d0]     = *(const int4*)src;
    *(int4*)&tile[sl][d0 + 8] = *(const int4*)(src + 8);
    __syncthreads();
    int dl = t >> 2, s0 = (t & 3) << 4;
    __align__(16) unsigned short tmp[16];
    #pragma unroll
    for (int i = 0; i < 16; i++) tmp[i] = tile[s0 + i][dl];
    unsigned short* dst = vt + (size_t)bh * (64 * SSN) + (size_t)dl * SSN + st * 64 + s0;
    *(int4*)dst       = *(const int4*)tmp;
    *(int4*)(dst + 8) = *(const int4*)(tmp + 8);
}

// -------- in-place row softmax over 1024 f32 --------
__global__ __launch_bounds__(256) void softmax_k(float* __restrict__ sc) {
    size_t row = blockIdx.x;
    float* p = sc + row * SSN;
    int t = threadIdx.x;
    float4 v = ((const float4*)p)[t];
    float mx = fmaxf(fmaxf(v.x, v.y), fmaxf(v.z, v.w));
    mx = blockReduceMax(mx);
    float e0 = __expf(v.x - mx), e1 = __expf(v.y - mx);
    float e2 = __expf(v.z - mx), e3 = __expf(v.w - mx);
    float s = blockReduceSum(e0 + e1 + e2 + e3);
    float inv = 1.0f / s;
    float4 o; o.x = e0 * inv; o.y = e1 * inv; o.z = e2 * inv; o.w = e3 * inv;
    ((float4*)p)[t] = o;
}

// -------- overwrite "uniform" attention rows with mean_k V --------
__global__ __launch_bounds__(256) void fixup_k(const unsigned short* __restrict__ vt,
                                               unsigned short* __restrict__ o, int mtype) {
    __shared__ float sh[4][64];
    int bh = blockIdx.x;
    int b = bh >> 4, h = bh & 15;
    int t = threadIdx.x;
    int d = t & 63, c = t >> 6;
    const unsigned short* row = vt + (size_t)bh * (64 * SSN) + (size_t)d * SSN + c * 256;
    float s = 0.f;
    for (int i = 0; i < 256; i += 8) {
        int4 q = *(const int4*)(row + i);
        const unsigned short* u = (const unsigned short*)&q;
        #pragma unroll
        for (int j = 0; j < 8; j++) s += bf2f(u[j]);
    }
    sh[c][d] = s;
    __syncthreads();
    if (c == 0) {
        float tot = sh[0][d] + sh[1][d] + sh[2][d] + sh[3][d];
        unsigned short mv = f2bf(tot * (1.0f / 1024.0f));
        size_t base = (size_t)b * SSN * DD + (size_t)h * 64 + d;
        if (mtype == 0) {
            for (int r = 480; r < 512; r++) o[base + (size_t)r * DD] = mv;
        } else {
            o[base + (size_t)511 * DD] = mv;
            for (int cc = 0; cc < 32; cc++)
                o[base + (size_t)(512 + cc * 16 + 15) * DD] = mv;
        }
    }
}

// -------- gather final rows (513..1023 per batch) to bf16 --------
__global__ __launch_bounds__(256) void gather_xl_k(const float* __restrict__ x,
                                                   unsigned short* __restrict__ xl) {
    int r = blockIdx.x;                 // 0..1021
    int b = r / 511, i = r % 511;
    int d = threadIdx.x * 4;
    float4 v = *(const float4*)(x + (size_t)(b * SSN + 513 + i) * DD + d);
    ushort4 o;
    o.x = f2bf(v.x); o.y = f2bf(v.y); o.z = f2bf(v.z); o.w = f2bf(v.w);
    *(ushort4*)(xl + (size_t)r * DD + d) = o;
}

// -------- per-row loss: logsumexp - target logit --------
__global__ __launch_bounds__(256) void loss_row_k(const float* __restrict__ logits,
                                                  const int* __restrict__ tok,
                                                  float* __restrict__ rowloss) {
    int r = blockIdx.x;
    const float* p = logits + (size_t)r * VV;
    int t = threadIdx.x;
    float mx = -1e30f;
    for (int i = t; i < VV; i += 256) mx = fmaxf(mx, p[i]);
    mx = blockReduceMax(mx);
    float s = 0.f;
    for (int i = t; i < VV; i += 256) s += __expf(p[i] - mx);
    s = blockReduceSum(s);
    if (t == 0) {
        int b = r / 511, i2 = r % 511;
        int tgt = tok[b * TTN + i2];
        rowloss[r] = (logf(s) + mx) - p[tgt];
    }
}

__global__ __launch_bounds__(256) void loss_final_k(const float* __restrict__ rowloss,
                                                    float* __restrict__ out) {
    int t = threadIdx.x;
    float s = 0.f;
    for (int i = t; i < 1022; i += 256) s += rowloss[i];
    s = blockReduceSum(s);
    if (t == 0) out[0] = s * (1.0f / 1022.0f);
}

// ---------------- generic MFMA GEMM ----------------
// C[M,N] = alpha * A[M,K] @ Bt[N,K]^T + bias
// EPI: 0=f32 store, 1=bf16 store, 2=gelu->bf16, 3=f32 += (residual)
// ADT: 0 = A bf16, 1 = A f32 (converted during staging)
// batch: z -> (bb=z>>4, hh=z&15); offsets in ELEMENTS.
template <int EPI, int ADT>
__global__ __launch_bounds__(256) void gemm_k(
    const void* __restrict__ Ap, long lda, long zAb, long zAh,
    const unsigned short* __restrict__ Bt, long ldb, long zBb, long zBh,
    void* __restrict__ Cp, long ldc, long zCb, long zCh,
    const float* __restrict__ bias,
    int M, int N, int K, float alpha) {
    __shared__ __align__(16) unsigned short As[128][40];
    __shared__ __align__(16) unsigned short Bs[128][40];

    const int z = blockIdx.z;
    const int bb = z >> 4, hh = z & 15;
    const size_t aoff = (size_t)bb * zAb + (size_t)hh * zAh;
    const size_t boff = (size_t)bb * zBb + (size_t)hh * zBh;
    const size_t coff = (size_t)bb * zCb + (size_t)hh * zCh;

    const int t = threadIdx.x;
    const int brow = blockIdx.y * 128;
    const int bcol = blockIdx.x * 128;

    const int lane = t & 63;
    const int wv = t >> 6;
    const int wr = (wv >> 1) * 64;
    const int wc = (wv & 1) * 64;
    const int fr = lane & 15;
    const int g8 = (lane >> 4) * 8;

    f32x4 acc[4][4] = {};

    const int srow = t >> 1;
    const int scol = (t & 1) << 4;

    for (int k0 = 0; k0 < K; k0 += 32) {
        __syncthreads();
        {   // stage A tile (128 x 32)
            const int gr = brow + srow;
            int4 v0{}; int4 v1{};
            if (gr < M) {
                if constexpr (ADT == 0) {
                    const unsigned short* a =
                        (const unsigned short*)Ap + aoff + (size_t)gr * lda + k0 + scol;
                    v0 = *(const int4*)a;
                    v1 = *(const int4*)(a + 8);
                } else {
                    const float* a = (const float*)Ap + aoff + (size_t)gr * lda + k0 + scol;
                    float4 f0 = *(const float4*)a;
                    float4 f1 = *(const float4*)(a + 4);
                    float4 f2 = *(const float4*)(a + 8);
                    float4 f3 = *(const float4*)(a + 12);
                    __align__(16) unsigned short tmp[16];
                    tmp[0]=f2bf(f0.x); tmp[1]=f2bf(f0.y); tmp[2]=f2bf(f0.z); tmp[3]=f2bf(f0.w);
                    tmp[4]=f2bf(f1.x); tmp[5]=f2bf(f1.y); tmp[6]=f2bf(f1.z); tmp[7]=f2bf(f1.w);
                    tmp[8]=f2bf(f2.x); tmp[9]=f2bf(f2.y); tmp[10]=f2bf(f2.z); tmp[11]=f2bf(f2.w);
                    tmp[12]=f2bf(f3.x); tmp[13]=f2bf(f3.y); tmp[14]=f2bf(f3.z); tmp[15]=f2bf(f3.w);
                    v0 = *(const int4*)&tmp[0];
                    v1 = *(const int4*)&tmp[8];
                }
            }
            *(int4*)&As[srow][scol]     = v0;
            *(int4*)&As[srow][scol + 8] = v1;
        }
        {   // stage Bt tile (128 x 32) — rows are output columns
            const int gc = bcol + srow;
            int4 v0{}; int4 v1{};
            if (gc < N) {
                const unsigned short* bsrc = Bt + boff + (size_t)gc * ldb + k0 + scol;
                v0 = *(const int4*)bsrc;
                v1 = *(const int4*)(bsrc + 8);
            }
            *(int4*)&Bs[srow][scol]     = v0;
            *(int4*)&Bs[srow][scol + 8] = v1;
        }
        __syncthreads();

        short8 af[4], bf[4];
        #pragma unroll
        for (int m = 0; m < 4; m++) af[m] = *(const short8*)&As[wr + m * 16 + fr][g8];
        #pragma unroll
        for (int n = 0; n < 4; n++) bf[n] = *(const short8*)&Bs[wc + n * 16 + fr][g8];
        #pragma unroll
        for (int m = 0; m < 4; m++)
            #pragma unroll
            for (int n = 0; n < 4; n++)
                acc[m][n] = __builtin_amdgcn_mfma_f32_16x16x32_bf16(af[m], bf[n], acc[m][n], 0, 0, 0);
    }

    const int g4 = (lane >> 4) * 4;
    #pragma unroll
    for (int n = 0; n < 4; n++) {
        const int col = bcol + wc + n * 16 + fr;
        if (col >= N) continue;
        const float bv = bias ? bias[col] : 0.f;
        #pragma unroll
        for (int m = 0; m < 4; m++) {
            #pragma unroll
            for (int j = 0; j < 4; j++) {
                const int row = brow + wr + m * 16 + g4 + j;
                if (row >= M) continue;
                float v = acc[m][n][j] * alpha + bv;
                const size_t ci = coff + (size_t)row * ldc + col;
                if (EPI == 0) {
                    ((float*)Cp)[ci] = v;
                } else if (EPI == 1) {
                    ((unsigned short*)Cp)[ci] = f2bf(v);
                } else if (EPI == 2) {
                    float gl = 0.5f * v * (1.0f + erff(v * 0.70710678118654752f));
                    ((unsigned short*)Cp)[ci] = f2bf(gl);
                } else {
                    ((float*)Cp)[ci] += v;
                }
            }
        }
    }
}

// ---------------- host orchestration ----------------
extern "C" void kernel_launch(void* const* d_in, const int* in_sizes, int n_in,
                              void* d_out, int out_size, void* d_ws, size_t ws_size,
                              hipStream_t stream) {
    const int*   tok  = (const int*)d_in[0];
    const float* temb = (const float*)d_in[1];
    const float* pemb = (const float*)d_in[2];
    const float* mtok = (const float*)d_in[3];
    const float* W[24];
    for (int i = 0; i < 24; i++) W[i] = (const float*)d_in[4 + i];
    // per group order: ln1g ln1b wqkv bqkv wo bo ln2g ln2b w1 b1 w2 b2

    // workspace layout (bytes; ~252.2 MB total)
    char* ws = (char*)d_ws;
    float*          x      = (float*)(ws + 0);                  //  8,388,608
    unsigned short* xb     = (unsigned short*)(ws + 8388608);   //  4,194,304
    unsigned short* qkvb   = (unsigned short*)(ws + 12582912);  // 12,582,912
    unsigned short* vt     = (unsigned short*)(ws + 25165824);  //  4,194,304
    unsigned short* o      = (unsigned short*)(ws + 29360128);  //  4,194,304
    unsigned short* g      = (unsigned short*)(ws + 33554432);  // 16,777,216
    unsigned short* wsc    = (unsigned short*)(ws + 50331648);  // 65,536,000
    float*          scores = (float*)(ws + 115867648);          // 134,217,728 (reused as logits)
    unsigned short* xl     = (unsigned short*)(ws + 250085376); //  2,093,056
    float*          rowloss= (float*)(ws + 252178432);          //  4,088

    embed_k<<<NRN, 256, 0, stream>>>(tok, temb, pemb, mtok, x);

    for (int l = 0; l < 6; l++) {
        const int grp = (l < 4) ? 0 : 1;
        const int li  = (l < 4) ? l : l - 4;
        const float* const* P = W + grp * 12;
        const float* ln1g = P[0] + (size_t)li * DD;
        const float* ln1b = P[1] + (size_t)li * DD;
        const float* wqkv = P[2] + (size_t)li * DD * 3 * DD;
        const float* bqkv = P[3] + (size_t)li * 3 * DD;
        const float* wo   = P[4] + (size_t)li * DD * DD;
        const float* bo   = P[5] + (size_t)li * DD;
        const float* ln2g = P[6] + (size_t)li * DD;
        const float* ln2b = P[7] + (size_t)li * DD;
        const float* w1   = P[8] + (size_t)li * DD * DFFN;
        const float* b1   = P[9] + (size_t)li * DFFN;
        const float* w2   = P[10] + (size_t)li * DFFN * DD;
        const float* b2   = P[11] + (size_t)li * DD;

        // ---- attention ----
        ln_k<<<NRN, 256, 0, stream>>>(x, ln1g, ln1b, xb);
        convT_k<<<dim3(3 * DD / 32, DD / 32), dim3(32, 8), 0, stream>>>(wqkv, wsc, DD, 3 * DD);
        gemm_k<1, 0><<<dim3(24, 16, 1), 256, 0, stream>>>(
            xb, DD, 0, 0, wsc, DD, 0, 0, qkvb, 3 * DD, 0, 0, bqkv, NRN, 3 * DD, DD, 1.0f);
        vtr_k<<<dim3(32, 16), 256, 0, stream>>>(qkvb, vt);
        // scores = Q K^T / 8   (A = q-part, Bt = k-part rows)
        gemm_k<0, 0><<<dim3(8, 8, 32), 256, 0, stream>>>(
            qkvb, 3 * DD, 3145728, 64,
            qkvb + DD, 3 * DD, 3145728, 64,
            scores, SSN, 16777216, 1048576,
            nullptr, SSN, SSN, DHD, 0.125f);
        softmax_k<<<32 * SSN, 256, 0, stream>>>(scores);
        // o = P V   (A = probs f32, Bt = vt)
        gemm_k<1, 1><<<dim3(1, 8, 32), 256, 0, stream>>>(
            scores, SSN, 16777216, 1048576,
            vt, SSN, 1048576, 65536,
            o, DD, (long)SSN * DD, 64,
            nullptr, SSN, DHD, SSN, 1.0f);
        fixup_k<<<32, 256, 0, stream>>>(vt, o, grp);
        convT_k<<<dim3(DD / 32, DD / 32), dim3(32, 8), 0, stream>>>(wo, wsc, DD, DD);
        gemm_k<3, 0><<<dim3(8, 16, 1), 256, 0, stream>>>(
            o, DD, 0, 0, wsc, DD, 0, 0, x, DD, 0, 0, bo, NRN, DD, DD, 1.0f);

        // ---- ffn ----
        ln_k<<<NRN, 256, 0, stream>>>(x, ln2g, ln2b, xb);
        convT_k<<<dim3(DFFN / 32, DD / 32), dim3(32, 8), 0, stream>>>(w1, wsc, DD, DFFN);
        gemm_k<2, 0><<<dim3(32, 16, 1), 256, 0, stream>>>(
            xb, DD, 0, 0, wsc, DD, 0, 0, g, DFFN, 0, 0, b1, NRN, DFFN, DD, 1.0f);
        convT_k<<<dim3(DD / 32, DFFN / 32), dim3(32, 8), 0, stream>>>(w2, wsc, DFFN, DD);
        gemm_k<3, 0><<<dim3(8, 16, 1), 256, 0, stream>>>(
            g, DFFN, 0, 0, wsc, DFFN, 0, 0, x, DD, 0, 0, b2, NRN, DD, DFFN, 1.0f);
    }

    // ---- loss ----
    gather_xl_k<<<1022, 256, 0, stream>>>(x, xl);
    conv_k<<<16000, 256, 0, stream>>>(temb, wsc, (long)VV * DD);
    gemm_k<0, 0><<<dim3(250, 8, 1), 256, 0, stream>>>(
        xl, DD, 0, 0, wsc, DD, 0, 0, scores /*logits*/, VV, 0, 0,
        nullptr, 1022, VV, DD, 1.0f);
    loss_row_k<<<1022, 256, 0, stream>>>(scores, tok, rowloss);
    loss_final_k<<<1, 256, 0, stream>>>(rowloss, (float*)d_out);
}

// Round 2
// 2211.342 us; speedup vs baseline: 1.2548x; 1.2548x over previous
//
#include <hip/hip_runtime.h>
#include <hip/hip_bf16.h>
#include <math.h>

// ---------------- problem constants ----------------
#define DD   1024
#define HHN  16
#define DHD  64
#define DFFN 4096
#define VV   32000
#define BBN  2
#define TTN  512
#define SSN  1024      // 2T
#define NRN  2048      // B*S

typedef __attribute__((ext_vector_type(8))) short short8;
typedef __attribute__((ext_vector_type(4))) float f32x4;

__device__ __forceinline__ unsigned short f2bf(float f) {
    __hip_bfloat16 h = __float2bfloat16(f);
    return __builtin_bit_cast(unsigned short, h);
}
__device__ __forceinline__ float bf2f(unsigned short u) {
    return __bfloat162float(__builtin_bit_cast(__hip_bfloat16, u));
}

__device__ __forceinline__ float blockReduceSum(float v) {
    __shared__ float sh[4];
    #pragma unroll
    for (int o = 1; o < 64; o <<= 1) v += __shfl_xor(v, o, 64);
    int lane = threadIdx.x & 63, wv = threadIdx.x >> 6;
    __syncthreads();
    if (lane == 0) sh[wv] = v;
    __syncthreads();
    return sh[0] + sh[1] + sh[2] + sh[3];
}

// ---------------- embedding ----------------
__global__ __launch_bounds__(256) void embed_k(const int* __restrict__ tok,
                                               const float* __restrict__ temb,
                                               const float* __restrict__ pemb,
                                               const float* __restrict__ mtok,
                                               float* __restrict__ x) {
    int row = blockIdx.x;               // 0..2047
    int b = row >> 10, s = row & 1023;
    int d = threadIdx.x * 4;
    const float* src;
    const float* pe;
    if (s < TTN) {
        int id = tok[b * TTN + s];
        src = temb + (size_t)id * DD + d;
        pe  = pemb + (size_t)s * DD + d;
    } else {
        int sm = s - TTN;
        src = mtok + (size_t)(sm & 15) * DD + d;
        pe  = pemb + (size_t)sm * DD + d;
    }
    float4 v = *(const float4*)src;
    float4 p = *(const float4*)pe;
    v.x += p.x; v.y += p.y; v.z += p.z; v.w += p.w;
    *(float4*)(x + (size_t)row * DD + d) = v;
}

// ---------------- layernorm (f32 in -> bf16 out) ----------------
__global__ __launch_bounds__(256) void ln_k(const float* __restrict__ x,
                                            const float* __restrict__ g,
                                            const float* __restrict__ b,
                                            unsigned short* __restrict__ out) {
    int row = blockIdx.x;
    int d = threadIdx.x * 4;
    const float4 v = *(const float4*)(x + (size_t)row * DD + d);
    float s  = v.x + v.y + v.z + v.w;
    float ss = v.x * v.x + v.y * v.y + v.z * v.z + v.w * v.w;
    s  = blockReduceSum(s);
    ss = blockReduceSum(ss);
    float mu  = s * (1.0f / DD);
    float var = ss * (1.0f / DD) - mu * mu;
    float inv = rsqrtf(var + 1e-5f);
    const float4 gg = *(const float4*)(g + d);
    const float4 bb = *(const float4*)(b + d);
    ushort4 o;
    o.x = f2bf((v.x - mu) * inv * gg.x + bb.x);
    o.y = f2bf((v.y - mu) * inv * gg.y + bb.y);
    o.z = f2bf((v.z - mu) * inv * gg.z + bb.z);
    o.w = f2bf((v.w - mu) * inv * gg.w + bb.w);
    *(ushort4*)(out + (size_t)row * DD + d) = o;
}

// -------- transpose-convert weight: f32 [K,N] -> bf16 [N,K] --------
__global__ void convT_k(const float* __restrict__ w, unsigned short* __restrict__ wt,
                        int K, int N) {
    __shared__ float tile[32][33];
    int n0 = blockIdx.x * 32, k0 = blockIdx.y * 32;
    int tx = threadIdx.x, ty = threadIdx.y;  // (32,8)
    #pragma unroll
    for (int j = 0; j < 4; j++)
        tile[ty + j * 8][tx] = w[(size_t)(k0 + ty + j * 8) * N + n0 + tx];
    __syncthreads();
    #pragma unroll
    for (int j = 0; j < 4; j++)
        wt[(size_t)(n0 + ty + j * 8) * K + k0 + tx] = f2bf(tile[tx][ty + j * 8]);
}

// -------- V^T: qkvb v-part [s, h*64+d] -> vt [bh][d][s] --------
__global__ __launch_bounds__(256) void vtr_k(const unsigned short* __restrict__ qkvb,
                                             unsigned short* __restrict__ vt) {
    __shared__ __align__(16) unsigned short tile[64][72];
    int bh = blockIdx.x, st = blockIdx.y;
    int b = bh >> 4, h = bh & 15;
    int t = threadIdx.x;
    int sl = t >> 2, d0 = (t & 3) << 4;
    const unsigned short* src =
        qkvb + (size_t)(b * SSN + st * 64 + sl) * (3 * DD) + 2 * DD + h * 64 + d0;
    *(int4*)&tile[sl][d0]     = *(const int4*)src;
    *(int4*)&tile[sl][d0 + 8] = *(const int4*)(src + 8);
    __syncthreads();
    int dl = t >> 2, s0 = (t & 3) << 4;
    __align__(16) unsigned short tmp[16];
    #pragma unroll
    for (int i = 0; i < 16; i++) tmp[i] = tile[s0 + i][dl];
    unsigned short* dst = vt + (size_t)bh * (64 * SSN) + (size_t)dl * SSN + st * 64 + s0;
    *(int4*)dst       = *(const int4*)tmp;
    *(int4*)(dst + 8) = *(const int4*)(tmp + 8);
}

// ---------------- fused flash attention ----------------
// grid: 256 blocks = (bh=blk>>3, qtile=blk&7); 4 waves, each owns 32 q-rows.
__global__ __launch_bounds__(256, 1) void flash_k(
    const unsigned short* __restrict__ qkvb,   // [B*S][3D] bf16
    const unsigned short* __restrict__ vt,     // [bh][64][1024] bf16
    unsigned short* __restrict__ o) {          // [B*S][D] bf16
    __shared__ __align__(16) unsigned short Qs[128][72];
    __shared__ __align__(16) unsigned short Ks[128][72];
    __shared__ __align__(16) unsigned short Vs[64][136];
    __shared__ __align__(16) unsigned short Ps[128][136];

    const int blk = blockIdx.x;
    const int bh = blk >> 3, qt = blk & 7;
    const int b = bh >> 4, h = bh & 15;
    const int t = threadIdx.x;
    const int lane = t & 63;
    const int w = t >> 6;
    const int fr = lane & 15;
    const int g8 = (lane >> 4) * 8;
    const int g4 = (lane >> 4) * 4;

    {   // stage Q tile (128 x 64)
        const int r = t >> 1, c0 = (t & 1) * 32;
        const unsigned short* src =
            qkvb + (size_t)(b * SSN + qt * 128 + r) * 3072 + h * 64 + c0;
        *(int4*)&Qs[r][c0]      = *(const int4*)(src);
        *(int4*)&Qs[r][c0 + 8]  = *(const int4*)(src + 8);
        *(int4*)&Qs[r][c0 + 16] = *(const int4*)(src + 16);
        *(int4*)&Qs[r][c0 + 24] = *(const int4*)(src + 24);
    }
    __syncthreads();
    short8 aq[2][2];
    #pragma unroll
    for (int m = 0; m < 2; m++)
        #pragma unroll
        for (int kk = 0; kk < 2; kk++)
            aq[m][kk] = *(const short8*)&Qs[w * 32 + m * 16 + fr][kk * 32 + g8];

    float mrun[2][4], lrun[2][4];
    f32x4 accO[2][4] = {};
    #pragma unroll
    for (int m = 0; m < 2; m++)
        #pragma unroll
        for (int j = 0; j < 4; j++) { mrun[m][j] = -1e30f; lrun[m][j] = 0.f; }

    for (int kt = 0; kt < 8; kt++) {
        __syncthreads();
        {   // stage K tile (128 x 64)
            const int r = t >> 1, c0 = (t & 1) * 32;
            const unsigned short* src =
                qkvb + (size_t)(b * SSN + kt * 128 + r) * 3072 + DD + h * 64 + c0;
            *(int4*)&Ks[r][c0]      = *(const int4*)(src);
            *(int4*)&Ks[r][c0 + 8]  = *(const int4*)(src + 8);
            *(int4*)&Ks[r][c0 + 16] = *(const int4*)(src + 16);
            *(int4*)&Ks[r][c0 + 24] = *(const int4*)(src + 24);
        }
        {   // stage V^T tile (64 x 128)
            const int d = t >> 2, c0 = (t & 3) * 32;
            const unsigned short* src =
                vt + (size_t)bh * 65536 + (size_t)d * SSN + kt * 128 + c0;
            *(int4*)&Vs[d][c0]      = *(const int4*)(src);
            *(int4*)&Vs[d][c0 + 8]  = *(const int4*)(src + 8);
            *(int4*)&Vs[d][c0 + 16] = *(const int4*)(src + 16);
            *(int4*)&Vs[d][c0 + 24] = *(const int4*)(src + 24);
        }
        __syncthreads();

        short8 bk[8][2];
        #pragma unroll
        for (int n = 0; n < 8; n++)
            #pragma unroll
            for (int kk = 0; kk < 2; kk++)
                bk[n][kk] = *(const short8*)&Ks[n * 16 + fr][kk * 32 + g8];

        #pragma unroll
        for (int m = 0; m < 2; m++) {
            f32x4 a2[8] = {};
            #pragma unroll
            for (int n = 0; n < 8; n++) {
                a2[n] = __builtin_amdgcn_mfma_f32_16x16x32_bf16(aq[m][0], bk[n][0], a2[n], 0, 0, 0);
                a2[n] = __builtin_amdgcn_mfma_f32_16x16x32_bf16(aq[m][1], bk[n][1], a2[n], 0, 0, 0);
            }
            #pragma unroll
            for (int j = 0; j < 4; j++) {
                float tm = a2[0][j];
                #pragma unroll
                for (int n = 1; n < 8; n++) tm = fmaxf(tm, a2[n][j]);
                tm *= 0.125f;
                #pragma unroll
                for (int o2 = 1; o2 < 16; o2 <<= 1) tm = fmaxf(tm, __shfl_xor(tm, o2, 64));
                const float mn = fmaxf(mrun[m][j], tm);
                const float alpha = __expf(mrun[m][j] - mn);
                mrun[m][j] = mn;
                float rs = 0.f;
                #pragma unroll
                for (int n = 0; n < 8; n++) {
                    float pv = __expf(a2[n][j] * 0.125f - mn);
                    rs += pv;
                    Ps[w * 32 + m * 16 + g4 + j][n * 16 + fr] = f2bf(pv);
                }
                #pragma unroll
                for (int o2 = 1; o2 < 16; o2 <<= 1) rs += __shfl_xor(rs, o2, 64);
                lrun[m][j] = lrun[m][j] * alpha + rs;
                #pragma unroll
                for (int nd = 0; nd < 4; nd++) accO[m][nd][j] *= alpha;
            }
        }
        // PV: O[32 x 64] += P[32 x 128] @ V[128 x 64]
        #pragma unroll
        for (int kk = 0; kk < 4; kk++) {
            short8 pa0 = *(const short8*)&Ps[w * 32 + fr][kk * 32 + g8];
            short8 pa1 = *(const short8*)&Ps[w * 32 + 16 + fr][kk * 32 + g8];
            #pragma unroll
            for (int nd = 0; nd < 4; nd++) {
                short8 vb = *(const short8*)&Vs[nd * 16 + fr][kk * 32 + g8];
                accO[0][nd] = __builtin_amdgcn_mfma_f32_16x16x32_bf16(pa0, vb, accO[0][nd], 0, 0, 0);
                accO[1][nd] = __builtin_amdgcn_mfma_f32_16x16x32_bf16(pa1, vb, accO[1][nd], 0, 0, 0);
            }
        }
    }
    #pragma unroll
    for (int m = 0; m < 2; m++)
        #pragma unroll
        for (int nd = 0; nd < 4; nd++)
            #pragma unroll
            for (int j = 0; j < 4; j++) {
                float val = accO[m][nd][j] / lrun[m][j];
                int row = qt * 128 + w * 32 + m * 16 + g4 + j;
                int col = h * 64 + nd * 16 + fr;
                o[(size_t)(b * SSN + row) * DD + col] = f2bf(val);
            }
}

// -------- overwrite "uniform" attention rows with mean_k V --------
__global__ __launch_bounds__(256) void fixup_k(const unsigned short* __restrict__ vt,
                                               unsigned short* __restrict__ o, int mtype) {
    __shared__ float sh[4][64];
    int bh = blockIdx.x;
    int b = bh >> 4, h = bh & 15;
    int t = threadIdx.x;
    int d = t & 63, c = t >> 6;
    const unsigned short* row = vt + (size_t)bh * (64 * SSN) + (size_t)d * SSN + c * 256;
    float s = 0.f;
    for (int i = 0; i < 256; i += 8) {
        int4 q = *(const int4*)(row + i);
        const unsigned short* u = (const unsigned short*)&q;
        #pragma unroll
        for (int j = 0; j < 8; j++) s += bf2f(u[j]);
    }
    sh[c][d] = s;
    __syncthreads();
    if (c == 0) {
        float tot = sh[0][d] + sh[1][d] + sh[2][d] + sh[3][d];
        unsigned short mv = f2bf(tot * (1.0f / 1024.0f));
        size_t base = (size_t)b * SSN * DD + (size_t)h * 64 + d;
        if (mtype == 0) {
            for (int r = 480; r < 512; r++) o[base + (size_t)r * DD] = mv;
        } else {
            o[base + (size_t)511 * DD] = mv;
            for (int cc = 0; cc < 32; cc++)
                o[base + (size_t)(512 + cc * 16 + 15) * DD] = mv;
        }
    }
}

// -------- gather final rows (513..1023 per batch) to bf16 --------
__global__ __launch_bounds__(256) void gather_xl_k(const float* __restrict__ x,
                                                   unsigned short* __restrict__ xl) {
    int r = blockIdx.x;                 // 0..1021
    int b = r / 511, i = r % 511;
    int d = threadIdx.x * 4;
    float4 v = *(const float4*)(x + (size_t)(b * SSN + 513 + i) * DD + d);
    ushort4 o;
    o.x = f2bf(v.x); o.y = f2bf(v.y); o.z = f2bf(v.z); o.w = f2bf(v.w);
    *(ushort4*)(xl + (size_t)r * DD + d) = o;
}

// -------- per-row loss on bf16 logits: online logsumexp --------
__global__ __launch_bounds__(256) void loss_row_k(const unsigned short* __restrict__ logits,
                                                  const int* __restrict__ tok,
                                                  float* __restrict__ rowloss) {
    int r = blockIdx.x;
    const unsigned short* p = logits + (size_t)r * VV;
    int t = threadIdx.x;
    float mx = -1e30f, s = 0.f;
    for (int c = t; c < VV / 8; c += 256) {
        int4 q = *(const int4*)(p + c * 8);
        const unsigned short* u = (const unsigned short*)&q;
        #pragma unroll
        for (int j = 0; j < 8; j++) {
            float v = bf2f(u[j]);
            if (v > mx) { s *= __expf(mx - v); mx = v; }
            s += __expf(v - mx);
        }
    }
    #pragma unroll
    for (int o2 = 1; o2 < 64; o2 <<= 1) {
        float om = __shfl_xor(mx, o2, 64);
        float os = __shfl_xor(s, o2, 64);
        float m2 = fmaxf(mx, om);
        s = s * __expf(mx - m2) + os * __expf(om - m2);
        mx = m2;
    }
    __shared__ float shm[4], shs[4];
    int lane = t & 63, wv = t >> 6;
    if (lane == 0) { shm[wv] = mx; shs[wv] = s; }
    __syncthreads();
    if (t == 0) {
        float M = fmaxf(fmaxf(shm[0], shm[1]), fmaxf(shm[2], shm[3]));
        float S = shs[0] * __expf(shm[0] - M) + shs[1] * __expf(shm[1] - M)
                + shs[2] * __expf(shm[2] - M) + shs[3] * __expf(shm[3] - M);
        int b = r / 511, i2 = r % 511;
        int tgt = tok[b * TTN + i2];
        rowloss[r] = (logf(S) + M) - bf2f(p[tgt]);
    }
}

__global__ __launch_bounds__(256) void loss_final_k(const float* __restrict__ rowloss,
                                                    float* __restrict__ out) {
    int t = threadIdx.x;
    float s = 0.f;
    for (int i = t; i < 1022; i += 256) s += rowloss[i];
    s = blockReduceSum(s);
    if (t == 0) out[0] = s * (1.0f / 1022.0f);
}

// ---------------- generic MFMA GEMM ----------------
// C[M,N] = alpha * A[M,K] @ Bt[N,K]^T + bias
// EPI: 0=f32 store, 1=bf16 store, 2=gelu->bf16, 3=f32 += (residual)
// ADT/BDT: 0 = bf16, 1 = f32 (converted during staging)
// SWAP: 1 -> blockIdx.x indexes rows (consecutive blocks share B panel)
template <int EPI, int ADT, int BDT, int SWAP>
__global__ __launch_bounds__(256) void gemm_k(
    const void* __restrict__ Ap, long lda, long zAb, long zAh,
    const void* __restrict__ Btp, long ldb, long zBb, long zBh,
    void* __restrict__ Cp, long ldc, long zCb, long zCh,
    const float* __restrict__ bias,
    int M, int N, int K, float alpha) {
    __shared__ __align__(16) unsigned short As[128][40];
    __shared__ __align__(16) unsigned short Bs[128][40];

    const int z = blockIdx.z;
    const int bb = z >> 4, hh = z & 15;
    const size_t aoff = (size_t)bb * zAb + (size_t)hh * zAh;
    const size_t boff = (size_t)bb * zBb + (size_t)hh * zBh;
    const size_t coff = (size_t)bb * zCb + (size_t)hh * zCh;

    const int t = threadIdx.x;
    const int brow = (SWAP ? blockIdx.x : blockIdx.y) * 128;
    const int bcol = (SWAP ? blockIdx.y : blockIdx.x) * 128;

    const int lane = t & 63;
    const int wv = t >> 6;
    const int wr = (wv >> 1) * 64;
    const int wc = (wv & 1) * 64;
    const int fr = lane & 15;
    const int g8 = (lane >> 4) * 8;

    f32x4 acc[4][4] = {};

    const int srow = t >> 1;
    const int scol = (t & 1) << 4;

    for (int k0 = 0; k0 < K; k0 += 32) {
        __syncthreads();
        {   // stage A tile (128 x 32)
            const int gr = brow + srow;
            int4 v0{}; int4 v1{};
            if (gr < M) {
                if constexpr (ADT == 0) {
                    const unsigned short* a =
                        (const unsigned short*)Ap + aoff + (size_t)gr * lda + k0 + scol;
                    v0 = *(const int4*)a;
                    v1 = *(const int4*)(a + 8);
                } else {
                    const float* a = (const float*)Ap + aoff + (size_t)gr * lda + k0 + scol;
                    float4 f0 = *(const float4*)a;
                    float4 f1 = *(const float4*)(a + 4);
                    float4 f2 = *(const float4*)(a + 8);
                    float4 f3 = *(const float4*)(a + 12);
                    __align__(16) unsigned short tmp[16];
                    tmp[0]=f2bf(f0.x); tmp[1]=f2bf(f0.y); tmp[2]=f2bf(f0.z); tmp[3]=f2bf(f0.w);
                    tmp[4]=f2bf(f1.x); tmp[5]=f2bf(f1.y); tmp[6]=f2bf(f1.z); tmp[7]=f2bf(f1.w);
                    tmp[8]=f2bf(f2.x); tmp[9]=f2bf(f2.y); tmp[10]=f2bf(f2.z); tmp[11]=f2bf(f2.w);
                    tmp[12]=f2bf(f3.x); tmp[13]=f2bf(f3.y); tmp[14]=f2bf(f3.z); tmp[15]=f2bf(f3.w);
                    v0 = *(const int4*)&tmp[0];
                    v1 = *(const int4*)&tmp[8];
                }
            }
            *(int4*)&As[srow][scol]     = v0;
            *(int4*)&As[srow][scol + 8] = v1;
        }
        {   // stage Bt tile (128 x 32) — rows are output columns
            const int gc = bcol + srow;
            int4 v0{}; int4 v1{};
            if (gc < N) {
                if constexpr (BDT == 0) {
                    const unsigned short* bsrc =
                        (const unsigned short*)Btp + boff + (size_t)gc * ldb + k0 + scol;
                    v0 = *(const int4*)bsrc;
                    v1 = *(const int4*)(bsrc + 8);
                } else {
                    const float* bsrc = (const float*)Btp + boff + (size_t)gc * ldb + k0 + scol;
                    float4 f0 = *(const float4*)bsrc;
                    float4 f1 = *(const float4*)(bsrc + 4);
                    float4 f2 = *(const float4*)(bsrc + 8);
                    float4 f3 = *(const float4*)(bsrc + 12);
                    __align__(16) unsigned short tmp[16];
                    tmp[0]=f2bf(f0.x); tmp[1]=f2bf(f0.y); tmp[2]=f2bf(f0.z); tmp[3]=f2bf(f0.w);
                    tmp[4]=f2bf(f1.x); tmp[5]=f2bf(f1.y); tmp[6]=f2bf(f1.z); tmp[7]=f2bf(f1.w);
                    tmp[8]=f2bf(f2.x); tmp[9]=f2bf(f2.y); tmp[10]=f2bf(f2.z); tmp[11]=f2bf(f2.w);
                    tmp[12]=f2bf(f3.x); tmp[13]=f2bf(f3.y); tmp[14]=f2bf(f3.z); tmp[15]=f2bf(f3.w);
                    v0 = *(const int4*)&tmp[0];
                    v1 = *(const int4*)&tmp[8];
                }
            }
            *(int4*)&Bs[srow][scol]     = v0;
            *(int4*)&Bs[srow][scol + 8] = v1;
        }
        __syncthreads();

        short8 af[4], bf[4];
        #pragma unroll
        for (int m = 0; m < 4; m++) af[m] = *(const short8*)&As[wr + m * 16 + fr][g8];
        #pragma unroll
        for (int n = 0; n < 4; n++) bf[n] = *(const short8*)&Bs[wc + n * 16 + fr][g8];
        #pragma unroll
        for (int m = 0; m < 4; m++)
            #pragma unroll
            for (int n = 0; n < 4; n++)
                acc[m][n] = __builtin_amdgcn_mfma_f32_16x16x32_bf16(af[m], bf[n], acc[m][n], 0, 0, 0);
    }

    const int g4 = (lane >> 4) * 4;
    #pragma unroll
    for (int n = 0; n < 4; n++) {
        const int col = bcol + wc + n * 16 + fr;
        if (col >= N) continue;
        const float bv = bias ? bias[col] : 0.f;
        #pragma unroll
        for (int m = 0; m < 4; m++) {
            #pragma unroll
            for (int j = 0; j < 4; j++) {
                const int row = brow + wr + m * 16 + g4 + j;
                if (row >= M) continue;
                float v = acc[m][n][j] * alpha + bv;
                const size_t ci = coff + (size_t)row * ldc + col;
                if (EPI == 0) {
                    ((float*)Cp)[ci] = v;
                } else if (EPI == 1) {
                    ((unsigned short*)Cp)[ci] = f2bf(v);
                } else if (EPI == 2) {
                    float gl = 0.5f * v * (1.0f + erff(v * 0.70710678118654752f));
                    ((unsigned short*)Cp)[ci] = f2bf(gl);
                } else {
                    ((float*)Cp)[ci] += v;
                }
            }
        }
    }
}

// ---------------- host orchestration ----------------
extern "C" void kernel_launch(void* const* d_in, const int* in_sizes, int n_in,
                              void* d_out, int out_size, void* d_ws, size_t ws_size,
                              hipStream_t stream) {
    const int*   tok  = (const int*)d_in[0];
    const float* temb = (const float*)d_in[1];
    const float* pemb = (const float*)d_in[2];
    const float* mtok = (const float*)d_in[3];
    const float* W[24];
    for (int i = 0; i < 24; i++) W[i] = (const float*)d_in[4 + i];

    // workspace layout (bytes)
    char* ws = (char*)d_ws;
    float*          x      = (float*)(ws + 0);                  //  8,388,608
    unsigned short* xb     = (unsigned short*)(ws + 8388608);   //  4,194,304
    unsigned short* qkvb   = (unsigned short*)(ws + 12582912);  // 12,582,912
    unsigned short* vt     = (unsigned short*)(ws + 25165824);  //  4,194,304
    unsigned short* o      = (unsigned short*)(ws + 29360128);  //  4,194,304
    unsigned short* g      = (unsigned short*)(ws + 33554432);  // 16,777,216
    unsigned short* wsc    = (unsigned short*)(ws + 50331648);  //  weight scratch
    unsigned short* logits = (unsigned short*)(ws + 115867648); // 65,408,000 (bf16)
    unsigned short* xl     = (unsigned short*)(ws + 250085376); //  2,093,056
    float*          rowloss= (float*)(ws + 252178432);          //  4,088

    embed_k<<<NRN, 256, 0, stream>>>(tok, temb, pemb, mtok, x);

    for (int l = 0; l < 6; l++) {
        const int grp = (l < 4) ? 0 : 1;
        const int li  = (l < 4) ? l : l - 4;
        const float* const* P = W + grp * 12;
        const float* ln1g = P[0] + (size_t)li * DD;
        const float* ln1b = P[1] + (size_t)li * DD;
        const float* wqkv = P[2] + (size_t)li * DD * 3 * DD;
        const float* bqkv = P[3] + (size_t)li * 3 * DD;
        const float* wo   = P[4] + (size_t)li * DD * DD;
        const float* bo   = P[5] + (size_t)li * DD;
        const float* ln2g = P[6] + (size_t)li * DD;
        const float* ln2b = P[7] + (size_t)li * DD;
        const float* w1   = P[8] + (size_t)li * DD * DFFN;
        const float* b1   = P[9] + (size_t)li * DFFN;
        const float* w2   = P[10] + (size_t)li * DFFN * DD;
        const float* b2   = P[11] + (size_t)li * DD;

        // ---- attention ----
        ln_k<<<NRN, 256, 0, stream>>>(x, ln1g, ln1b, xb);
        convT_k<<<dim3(3 * DD / 32, DD / 32), dim3(32, 8), 0, stream>>>(wqkv, wsc, DD, 3 * DD);
        gemm_k<1, 0, 0, 0><<<dim3(24, 16, 1), 256, 0, stream>>>(
            xb, DD, 0, 0, wsc, DD, 0, 0, qkvb, 3 * DD, 0, 0, bqkv, NRN, 3 * DD, DD, 1.0f);
        vtr_k<<<dim3(32, 16), 256, 0, stream>>>(qkvb, vt);
        flash_k<<<256, 256, 0, stream>>>(qkvb, vt, o);
        fixup_k<<<32, 256, 0, stream>>>(vt, o, grp);
        convT_k<<<dim3(DD / 32, DD / 32), dim3(32, 8), 0, stream>>>(wo, wsc, DD, DD);
        gemm_k<3, 0, 0, 0><<<dim3(8, 16, 1), 256, 0, stream>>>(
            o, DD, 0, 0, wsc, DD, 0, 0, x, DD, 0, 0, bo, NRN, DD, DD, 1.0f);

        // ---- ffn ----
        ln_k<<<NRN, 256, 0, stream>>>(x, ln2g, ln2b, xb);
        convT_k<<<dim3(DFFN / 32, DD / 32), dim3(32, 8), 0, stream>>>(w1, wsc, DD, DFFN);
        gemm_k<2, 0, 0, 0><<<dim3(32, 16, 1), 256, 0, stream>>>(
            xb, DD, 0, 0, wsc, DD, 0, 0, g, DFFN, 0, 0, b1, NRN, DFFN, DD, 1.0f);
        convT_k<<<dim3(DD / 32, DFFN / 32), dim3(32, 8), 0, stream>>>(w2, wsc, DFFN, DD);
        gemm_k<3, 0, 0, 0><<<dim3(8, 16, 1), 256, 0, stream>>>(
            g, DFFN, 0, 0, wsc, DFFN, 0, 0, x, DD, 0, 0, b2, NRN, DD, DFFN, 1.0f);
    }

    // ---- loss ----
    gather_xl_k<<<1022, 256, 0, stream>>>(x, xl);
    // logits = xl @ temb^T, bf16 out; SWAP grid so consecutive blocks share vocab panel
    gemm_k<1, 0, 1, 1><<<dim3(8, 250, 1), 256, 0, stream>>>(
        xl, DD, 0, 0, temb, DD, 0, 0, logits, VV, 0, 0,
        nullptr, 1022, VV, DD, 1.0f);
    loss_row_k<<<1022, 256, 0, stream>>>(logits, tok, rowloss);
    loss_final_k<<<1, 256, 0, stream>>>(rowloss, (float*)d_out);
}

// Round 3
// 1830.909 us; speedup vs baseline: 1.5156x; 1.2078x over previous
//
#include <hip/hip_runtime.h>
#include <hip/hip_bf16.h>
#include <math.h>

// ---------------- problem constants ----------------
#define DD   1024
#define HHN  16
#define DHD  64
#define DFFN 4096
#define VV   32000
#define BBN  2
#define TTN  512
#define SSN  1024      // 2T
#define NRN  2048      // B*S

typedef __attribute__((ext_vector_type(8))) short short8;
typedef __attribute__((ext_vector_type(4))) float f32x4;

__device__ __forceinline__ unsigned short f2bf(float f) {
    __hip_bfloat16 h = __float2bfloat16(f);
    return __builtin_bit_cast(unsigned short, h);
}
__device__ __forceinline__ float bf2f(unsigned short u) {
    return __bfloat162float(__builtin_bit_cast(__hip_bfloat16, u));
}

__device__ __forceinline__ void glds16(const void* g, void* l) {
    __builtin_amdgcn_global_load_lds(
        (const __attribute__((address_space(1))) void*)g,
        (__attribute__((address_space(3))) void*)l,
        16, 0, 0);
}

__device__ __forceinline__ float blockReduceSum(float v) {
    __shared__ float sh[4];
    #pragma unroll
    for (int o = 1; o < 64; o <<= 1) v += __shfl_xor(v, o, 64);
    int lane = threadIdx.x & 63, wv = threadIdx.x >> 6;
    __syncthreads();
    if (lane == 0) sh[wv] = v;
    __syncthreads();
    return sh[0] + sh[1] + sh[2] + sh[3];
}

// ---------------- embedding ----------------
__global__ __launch_bounds__(256) void embed_k(const int* __restrict__ tok,
                                               const float* __restrict__ temb,
                                               const float* __restrict__ pemb,
                                               const float* __restrict__ mtok,
                                               float* __restrict__ x) {
    int row = blockIdx.x;               // 0..2047
    int b = row >> 10, s = row & 1023;
    int d = threadIdx.x * 4;
    const float* src;
    const float* pe;
    if (s < TTN) {
        int id = tok[b * TTN + s];
        src = temb + (size_t)id * DD + d;
        pe  = pemb + (size_t)s * DD + d;
    } else {
        int sm = s - TTN;
        src = mtok + (size_t)(sm & 15) * DD + d;
        pe  = pemb + (size_t)sm * DD + d;
    }
    float4 v = *(const float4*)src;
    float4 p = *(const float4*)pe;
    v.x += p.x; v.y += p.y; v.z += p.z; v.w += p.w;
    *(float4*)(x + (size_t)row * DD + d) = v;
}

// ---------------- layernorm (f32 in -> bf16 out) ----------------
__global__ __launch_bounds__(256) void ln_k(const float* __restrict__ x,
                                            const float* __restrict__ g,
                                            const float* __restrict__ b,
                                            unsigned short* __restrict__ out) {
    int row = blockIdx.x;
    int d = threadIdx.x * 4;
    const float4 v = *(const float4*)(x + (size_t)row * DD + d);
    float s  = v.x + v.y + v.z + v.w;
    float ss = v.x * v.x + v.y * v.y + v.z * v.z + v.w * v.w;
    s  = blockReduceSum(s);
    ss = blockReduceSum(ss);
    float mu  = s * (1.0f / DD);
    float var = ss * (1.0f / DD) - mu * mu;
    float inv = rsqrtf(var + 1e-5f);
    const float4 gg = *(const float4*)(g + d);
    const float4 bb = *(const float4*)(b + d);
    ushort4 o;
    o.x = f2bf((v.x - mu) * inv * gg.x + bb.x);
    o.y = f2bf((v.y - mu) * inv * gg.y + bb.y);
    o.z = f2bf((v.z - mu) * inv * gg.z + bb.z);
    o.w = f2bf((v.w - mu) * inv * gg.w + bb.w);
    *(ushort4*)(out + (size_t)row * DD + d) = o;
}

// -------- transpose-convert weight: f32 [K,N] -> bf16 [N,K] --------
__global__ void convT_k(const float* __restrict__ w, unsigned short* __restrict__ wt,
                        int K, int N) {
    __shared__ float tile[32][33];
    int n0 = blockIdx.x * 32, k0 = blockIdx.y * 32;
    int tx = threadIdx.x, ty = threadIdx.y;  // (32,8)
    #pragma unroll
    for (int j = 0; j < 4; j++)
        tile[ty + j * 8][tx] = w[(size_t)(k0 + ty + j * 8) * N + n0 + tx];
    __syncthreads();
    #pragma unroll
    for (int j = 0; j < 4; j++)
        wt[(size_t)(n0 + ty + j * 8) * K + k0 + tx] = f2bf(tile[tx][ty + j * 8]);
}

// -------- straight convert f32 -> bf16 --------
__global__ __launch_bounds__(256) void conv_k(const float* __restrict__ w,
                                              unsigned short* __restrict__ o, long n) {
    long i = ((long)blockIdx.x * 256 + threadIdx.x) * 8;
    if (i >= n) return;
    float4 a = *(const float4*)(w + i);
    float4 b = *(const float4*)(w + i + 4);
    __align__(16) unsigned short tmp[8];
    tmp[0] = f2bf(a.x); tmp[1] = f2bf(a.y); tmp[2] = f2bf(a.z); tmp[3] = f2bf(a.w);
    tmp[4] = f2bf(b.x); tmp[5] = f2bf(b.y); tmp[6] = f2bf(b.z); tmp[7] = f2bf(b.w);
    *(int4*)(o + i) = *(const int4*)tmp;
}

// -------- V^T: qkvb v-part [s, h*64+d] -> vt [bh][d][s] --------
__global__ __launch_bounds__(256) void vtr_k(const unsigned short* __restrict__ qkvb,
                                             unsigned short* __restrict__ vt) {
    __shared__ __align__(16) unsigned short tile[64][72];
    int bh = blockIdx.x, st = blockIdx.y;
    int b = bh >> 4, h = bh & 15;
    int t = threadIdx.x;
    int sl = t >> 2, d0 = (t & 3) << 4;
    const unsigned short* src =
        qkvb + (size_t)(b * SSN + st * 64 + sl) * (3 * DD) + 2 * DD + h * 64 + d0;
    *(int4*)&tile[sl][d0]     = *(const int4*)src;
    *(int4*)&tile[sl][d0 + 8] = *(const int4*)(src + 8);
    __syncthreads();
    int dl = t >> 2, s0 = (t & 3) << 4;
    __align__(16) unsigned short tmp[16];
    #pragma unroll
    for (int i = 0; i < 16; i++) tmp[i] = tile[s0 + i][dl];
    unsigned short* dst = vt + (size_t)bh * (64 * SSN) + (size_t)dl * SSN + st * 64 + s0;
    *(int4*)dst       = *(const int4*)tmp;
    *(int4*)(dst + 8) = *(const int4*)(tmp + 8);
}

// ---------------- fused flash attention ----------------
__global__ __launch_bounds__(256, 1) void flash_k(
    const unsigned short* __restrict__ qkvb,   // [B*S][3D] bf16
    const unsigned short* __restrict__ vt,     // [bh][64][1024] bf16
    unsigned short* __restrict__ o) {          // [B*S][D] bf16
    __shared__ __align__(16) unsigned short Qs[128][72];
    __shared__ __align__(16) unsigned short Ks[128][72];
    __shared__ __align__(16) unsigned short Vs[64][136];
    __shared__ __align__(16) unsigned short Ps[128][136];

    const int blk = blockIdx.x;
    const int bh = blk >> 3, qt = blk & 7;
    const int b = bh >> 4, h = bh & 15;
    const int t = threadIdx.x;
    const int lane = t & 63;
    const int w = t >> 6;
    const int fr = lane & 15;
    const int g8 = (lane >> 4) * 8;
    const int g4 = (lane >> 4) * 4;

    {   // stage Q tile (128 x 64)
        const int r = t >> 1, c0 = (t & 1) * 32;
        const unsigned short* src =
            qkvb + (size_t)(b * SSN + qt * 128 + r) * 3072 + h * 64 + c0;
        *(int4*)&Qs[r][c0]      = *(const int4*)(src);
        *(int4*)&Qs[r][c0 + 8]  = *(const int4*)(src + 8);
        *(int4*)&Qs[r][c0 + 16] = *(const int4*)(src + 16);
        *(int4*)&Qs[r][c0 + 24] = *(const int4*)(src + 24);
    }
    __syncthreads();
    short8 aq[2][2];
    #pragma unroll
    for (int m = 0; m < 2; m++)
        #pragma unroll
        for (int kk = 0; kk < 2; kk++)
            aq[m][kk] = *(const short8*)&Qs[w * 32 + m * 16 + fr][kk * 32 + g8];

    float mrun[2][4], lrun[2][4];
    f32x4 accO[2][4] = {};
    #pragma unroll
    for (int m = 0; m < 2; m++)
        #pragma unroll
        for (int j = 0; j < 4; j++) { mrun[m][j] = -1e30f; lrun[m][j] = 0.f; }

    for (int kt = 0; kt < 8; kt++) {
        __syncthreads();
        {   // stage K tile (128 x 64)
            const int r = t >> 1, c0 = (t & 1) * 32;
            const unsigned short* src =
                qkvb + (size_t)(b * SSN + kt * 128 + r) * 3072 + DD + h * 64 + c0;
            *(int4*)&Ks[r][c0]      = *(const int4*)(src);
            *(int4*)&Ks[r][c0 + 8]  = *(const int4*)(src + 8);
            *(int4*)&Ks[r][c0 + 16] = *(const int4*)(src + 16);
            *(int4*)&Ks[r][c0 + 24] = *(const int4*)(src + 24);
        }
        {   // stage V^T tile (64 x 128)
            const int d = t >> 2, c0 = (t & 3) * 32;
            const unsigned short* src =
                vt + (size_t)bh * 65536 + (size_t)d * SSN + kt * 128 + c0;
            *(int4*)&Vs[d][c0]      = *(const int4*)(src);
            *(int4*)&Vs[d][c0 + 8]  = *(const int4*)(src + 8);
            *(int4*)&Vs[d][c0 + 16] = *(const int4*)(src + 16);
            *(int4*)&Vs[d][c0 + 24] = *(const int4*)(src + 24);
        }
        __syncthreads();

        short8 bk[8][2];
        #pragma unroll
        for (int n = 0; n < 8; n++)
            #pragma unroll
            for (int kk = 0; kk < 2; kk++)
                bk[n][kk] = *(const short8*)&Ks[n * 16 + fr][kk * 32 + g8];

        #pragma unroll
        for (int m = 0; m < 2; m++) {
            f32x4 a2[8] = {};
            #pragma unroll
            for (int n = 0; n < 8; n++) {
                a2[n] = __builtin_amdgcn_mfma_f32_16x16x32_bf16(aq[m][0], bk[n][0], a2[n], 0, 0, 0);
                a2[n] = __builtin_amdgcn_mfma_f32_16x16x32_bf16(aq[m][1], bk[n][1], a2[n], 0, 0, 0);
            }
            #pragma unroll
            for (int j = 0; j < 4; j++) {
                float tm = a2[0][j];
                #pragma unroll
                for (int n = 1; n < 8; n++) tm = fmaxf(tm, a2[n][j]);
                tm *= 0.125f;
                #pragma unroll
                for (int o2 = 1; o2 < 16; o2 <<= 1) tm = fmaxf(tm, __shfl_xor(tm, o2, 64));
                const float mn = fmaxf(mrun[m][j], tm);
                const float alpha = __expf(mrun[m][j] - mn);
                mrun[m][j] = mn;
                float rs = 0.f;
                #pragma unroll
                for (int n = 0; n < 8; n++) {
                    float pv = __expf(a2[n][j] * 0.125f - mn);
                    rs += pv;
                    Ps[w * 32 + m * 16 + g4 + j][n * 16 + fr] = f2bf(pv);
                }
                #pragma unroll
                for (int o2 = 1; o2 < 16; o2 <<= 1) rs += __shfl_xor(rs, o2, 64);
                lrun[m][j] = lrun[m][j] * alpha + rs;
                #pragma unroll
                for (int nd = 0; nd < 4; nd++) accO[m][nd][j] *= alpha;
            }
        }
        // PV: O[32 x 64] += P[32 x 128] @ V[128 x 64]
        #pragma unroll
        for (int kk = 0; kk < 4; kk++) {
            short8 pa0 = *(const short8*)&Ps[w * 32 + fr][kk * 32 + g8];
            short8 pa1 = *(const short8*)&Ps[w * 32 + 16 + fr][kk * 32 + g8];
            #pragma unroll
            for (int nd = 0; nd < 4; nd++) {
                short8 vb = *(const short8*)&Vs[nd * 16 + fr][kk * 32 + g8];
                accO[0][nd] = __builtin_amdgcn_mfma_f32_16x16x32_bf16(pa0, vb, accO[0][nd], 0, 0, 0);
                accO[1][nd] = __builtin_amdgcn_mfma_f32_16x16x32_bf16(pa1, vb, accO[1][nd], 0, 0, 0);
            }
        }
    }
    #pragma unroll
    for (int m = 0; m < 2; m++)
        #pragma unroll
        for (int nd = 0; nd < 4; nd++)
            #pragma unroll
            for (int j = 0; j < 4; j++) {
                float val = accO[m][nd][j] / lrun[m][j];
                int row = qt * 128 + w * 32 + m * 16 + g4 + j;
                int col = h * 64 + nd * 16 + fr;
                o[(size_t)(b * SSN + row) * DD + col] = f2bf(val);
            }
}

// -------- overwrite "uniform" attention rows with mean_k V --------
__global__ __launch_bounds__(256) void fixup_k(const unsigned short* __restrict__ vt,
                                               unsigned short* __restrict__ o, int mtype) {
    __shared__ float sh[4][64];
    int bh = blockIdx.x;
    int b = bh >> 4, h = bh & 15;
    int t = threadIdx.x;
    int d = t & 63, c = t >> 6;
    const unsigned short* row = vt + (size_t)bh * (64 * SSN) + (size_t)d * SSN + c * 256;
    float s = 0.f;
    for (int i = 0; i < 256; i += 8) {
        int4 q = *(const int4*)(row + i);
        const unsigned short* u = (const unsigned short*)&q;
        #pragma unroll
        for (int j = 0; j < 8; j++) s += bf2f(u[j]);
    }
    sh[c][d] = s;
    __syncthreads();
    if (c == 0) {
        float tot = sh[0][d] + sh[1][d] + sh[2][d] + sh[3][d];
        unsigned short mv = f2bf(tot * (1.0f / 1024.0f));
        size_t base = (size_t)b * SSN * DD + (size_t)h * 64 + d;
        if (mtype == 0) {
            for (int r = 480; r < 512; r++) o[base + (size_t)r * DD] = mv;
        } else {
            o[base + (size_t)511 * DD] = mv;
            for (int cc = 0; cc < 32; cc++)
                o[base + (size_t)(512 + cc * 16 + 15) * DD] = mv;
        }
    }
}

// -------- gather final rows (513..1023 per batch) to bf16, pad to 1024 --------
__global__ __launch_bounds__(256) void gather_xl_k(const float* __restrict__ x,
                                                   unsigned short* __restrict__ xl) {
    int r = blockIdx.x;                 // 0..1023
    int d = threadIdx.x * 4;
    ushort4 o = {0, 0, 0, 0};
    if (r < 1022) {
        int b = r / 511, i = r % 511;
        float4 v = *(const float4*)(x + (size_t)(b * SSN + 513 + i) * DD + d);
        o.x = f2bf(v.x); o.y = f2bf(v.y); o.z = f2bf(v.z); o.w = f2bf(v.w);
    }
    *(ushort4*)(xl + (size_t)r * DD + d) = o;
}

// -------- per-row loss on bf16 logits: online logsumexp --------
__global__ __launch_bounds__(256) void loss_row_k(const unsigned short* __restrict__ logits,
                                                  const int* __restrict__ tok,
                                                  float* __restrict__ rowloss) {
    int r = blockIdx.x;
    const unsigned short* p = logits + (size_t)r * VV;
    int t = threadIdx.x;
    float mx = -1e30f, s = 0.f;
    for (int c = t; c < VV / 8; c += 256) {
        int4 q = *(const int4*)(p + c * 8);
        const unsigned short* u = (const unsigned short*)&q;
        #pragma unroll
        for (int j = 0; j < 8; j++) {
            float v = bf2f(u[j]);
            if (v > mx) { s *= __expf(mx - v); mx = v; }
            s += __expf(v - mx);
        }
    }
    #pragma unroll
    for (int o2 = 1; o2 < 64; o2 <<= 1) {
        float om = __shfl_xor(mx, o2, 64);
        float os = __shfl_xor(s, o2, 64);
        float m2 = fmaxf(mx, om);
        s = s * __expf(mx - m2) + os * __expf(om - m2);
        mx = m2;
    }
    __shared__ float shm[4], shs[4];
    int lane = t & 63, wv = t >> 6;
    if (lane == 0) { shm[wv] = mx; shs[wv] = s; }
    __syncthreads();
    if (t == 0) {
        float M = fmaxf(fmaxf(shm[0], shm[1]), fmaxf(shm[2], shm[3]));
        float S = shs[0] * __expf(shm[0] - M) + shs[1] * __expf(shm[1] - M)
                + shs[2] * __expf(shm[2] - M) + shs[3] * __expf(shm[3] - M);
        int b = r / 511, i2 = r % 511;
        int tgt = tok[b * TTN + i2];
        rowloss[r] = (logf(S) + M) - bf2f(p[tgt]);
    }
}

__global__ __launch_bounds__(256) void loss_final_k(const float* __restrict__ rowloss,
                                                    float* __restrict__ out) {
    int t = threadIdx.x;
    float s = 0.f;
    for (int i = t; i < 1022; i += 256) s += rowloss[i];
    s = blockReduceSum(s);
    if (t == 0) out[0] = s * (1.0f / 1022.0f);
}

// ---------------- m97-structure MFMA GEMM ----------------
// C[M,N] = A[M,K] @ Bt[N,K]^T + bias.  All bf16 operands, f32 accumulate.
// M,N,K multiples of 128/128/32. Linear grid MT*NT blocks, XCD-swizzled,
// logical order mt-fastest (B-panel stays resident in one XCD's L2).
// EPI: 0=f32 store, 1=bf16 store, 2=gelu->bf16, 3=f32 +=
template <int EPI>
__global__ __launch_bounds__(256) void gemm_k(
    const unsigned short* __restrict__ A, long lda,
    const unsigned short* __restrict__ Bt, long ldb,
    void* __restrict__ Cp, long ldc,
    const float* __restrict__ bias,
    int MT, int K) {
    __shared__ __align__(16) unsigned short As[128][32];
    __shared__ __align__(16) unsigned short Bs[128][32];

    // bijective XCD swizzle (m204)
    const int nwg = gridDim.x;
    const int q = nwg >> 3, r = nwg & 7;
    const int xcd = blockIdx.x & 7, lin = blockIdx.x >> 3;
    const int wg = (xcd < r ? xcd * (q + 1) : r * (q + 1) + (xcd - r) * q) + lin;
    const int brow = (wg % MT) * 128;
    const int bcol = (wg / MT) * 128;

    const int t = threadIdx.x;
    const int lane = t & 63;
    const int w = t >> 6;
    const int fr = lane & 15;
    const int g8 = (lane >> 4) * 8;

    // staging assignment: wave w, issue i covers rows [(w*2+i)*16, +16)
    const int sr0 = (w * 2 + 0) * 16 + (lane >> 2);
    const int sr1 = (w * 2 + 1) * 16 + (lane >> 2);
    const int sc  = (lane & 3) * 8;
    const unsigned short* aP0 = A + (size_t)(brow + sr0) * lda + sc;
    const unsigned short* aP1 = A + (size_t)(brow + sr1) * lda + sc;
    const unsigned short* bP0 = Bt + (size_t)(bcol + sr0) * ldb + sc;
    const unsigned short* bP1 = Bt + (size_t)(bcol + sr1) * ldb + sc;
    unsigned short* lA0 = &As[(w * 2 + 0) * 16][0];
    unsigned short* lA1 = &As[(w * 2 + 1) * 16][0];
    unsigned short* lB0 = &Bs[(w * 2 + 0) * 16][0];
    unsigned short* lB1 = &Bs[(w * 2 + 1) * 16][0];

    f32x4 acc[4][4] = {};

    for (int k0 = 0; k0 < K; k0 += 32) {
        glds16(aP0, lA0);
        glds16(aP1, lA1);
        glds16(bP0, lB0);
        glds16(bP1, lB1);
        aP0 += 32; aP1 += 32; bP0 += 32; bP1 += 32;
        __syncthreads();

        short8 af[4], bf[4];
        #pragma unroll
        for (int m = 0; m < 4; m++) af[m] = *(const short8*)&As[((w >> 1) * 64) + m * 16 + fr][g8];
        #pragma unroll
        for (int n = 0; n < 4; n++) bf[n] = *(const short8*)&Bs[((w & 1) * 64) + n * 16 + fr][g8];
        #pragma unroll
        for (int m = 0; m < 4; m++)
            #pragma unroll
            for (int n = 0; n < 4; n++)
                acc[m][n] = __builtin_amdgcn_mfma_f32_16x16x32_bf16(af[m], bf[n], acc[m][n], 0, 0, 0);
        __syncthreads();
    }

    const int wr = (w >> 1) * 64;
    const int wc = (w & 1) * 64;
    const int g4 = (lane >> 4) * 4;
    #pragma unroll
    for (int n = 0; n < 4; n++) {
        const int col = bcol + wc + n * 16 + fr;
        const float bv = bias ? bias[col] : 0.f;
        #pragma unroll
        for (int m = 0; m < 4; m++) {
            #pragma unroll
            for (int j = 0; j < 4; j++) {
                const int row = brow + wr + m * 16 + g4 + j;
                float v = acc[m][n][j] + bv;
                const size_t ci = (size_t)row * ldc + col;
                if (EPI == 0) {
                    ((float*)Cp)[ci] = v;
                } else if (EPI == 1) {
                    ((unsigned short*)Cp)[ci] = f2bf(v);
                } else if (EPI == 2) {
                    float gl = 0.5f * v * (1.0f + erff(v * 0.70710678118654752f));
                    ((unsigned short*)Cp)[ci] = f2bf(gl);
                } else {
                    ((float*)Cp)[ci] += v;
                }
            }
        }
    }
}

// ---------------- host orchestration ----------------
extern "C" void kernel_launch(void* const* d_in, const int* in_sizes, int n_in,
                              void* d_out, int out_size, void* d_ws, size_t ws_size,
                              hipStream_t stream) {
    const int*   tok  = (const int*)d_in[0];
    const float* temb = (const float*)d_in[1];
    const float* pemb = (const float*)d_in[2];
    const float* mtok = (const float*)d_in[3];
    const float* W[24];
    for (int i = 0; i < 24; i++) W[i] = (const float*)d_in[4 + i];

    // workspace layout (bytes; ~201 MB total)
    char* ws = (char*)d_ws;
    float*          x      = (float*)(ws + 0);                   //  8,388,608
    unsigned short* xb     = (unsigned short*)(ws + 8388608);    //  4,194,304
    unsigned short* qkvb   = (unsigned short*)(ws + 12582912);   // 12,582,912
    unsigned short* vt     = (unsigned short*)(ws + 25165824);   //  4,194,304
    unsigned short* o      = (unsigned short*)(ws + 29360128);   //  4,194,304
    unsigned short* g      = (unsigned short*)(ws + 33554432);   // 16,777,216
    unsigned short* wsc    = (unsigned short*)(ws + 50331648);   // 16,777,216 (weight scratch)
    unsigned short* tembb  = (unsigned short*)(ws + 67108864);   // 65,536,000
    unsigned short* logits = (unsigned short*)(ws + 132644864);  // 65,536,000
    unsigned short* xl     = (unsigned short*)(ws + 198180864);  //  2,097,152
    float*          rowloss= (float*)(ws + 200278016);           //  4,096

    embed_k<<<NRN, 256, 0, stream>>>(tok, temb, pemb, mtok, x);
    conv_k<<<16000, 256, 0, stream>>>(temb, tembb, (long)VV * DD);

    for (int l = 0; l < 6; l++) {
        const int grp = (l < 4) ? 0 : 1;
        const int li  = (l < 4) ? l : l - 4;
        const float* const* P = W + grp * 12;
        const float* ln1g = P[0] + (size_t)li * DD;
        const float* ln1b = P[1] + (size_t)li * DD;
        const float* wqkv = P[2] + (size_t)li * DD * 3 * DD;
        const float* bqkv = P[3] + (size_t)li * 3 * DD;
        const float* wo   = P[4] + (size_t)li * DD * DD;
        const float* bo   = P[5] + (size_t)li * DD;
        const float* ln2g = P[6] + (size_t)li * DD;
        const float* ln2b = P[7] + (size_t)li * DD;
        const float* w1   = P[8] + (size_t)li * DD * DFFN;
        const float* b1   = P[9] + (size_t)li * DFFN;
        const float* w2   = P[10] + (size_t)li * DFFN * DD;
        const float* b2   = P[11] + (size_t)li * DD;

        // ---- attention ----
        ln_k<<<NRN, 256, 0, stream>>>(x, ln1g, ln1b, xb);
        convT_k<<<dim3(3 * DD / 32, DD / 32), dim3(32, 8), 0, stream>>>(wqkv, wsc, DD, 3 * DD);
        gemm_k<1><<<16 * 24, 256, 0, stream>>>(xb, DD, wsc, DD, qkvb, 3 * DD, bqkv, 16, DD);
        vtr_k<<<dim3(32, 16), 256, 0, stream>>>(qkvb, vt);
        flash_k<<<256, 256, 0, stream>>>(qkvb, vt, o);
        fixup_k<<<32, 256, 0, stream>>>(vt, o, grp);
        convT_k<<<dim3(DD / 32, DD / 32), dim3(32, 8), 0, stream>>>(wo, wsc, DD, DD);
        gemm_k<3><<<16 * 8, 256, 0, stream>>>(o, DD, wsc, DD, x, DD, bo, 16, DD);

        // ---- ffn ----
        ln_k<<<NRN, 256, 0, stream>>>(x, ln2g, ln2b, xb);
        convT_k<<<dim3(DFFN / 32, DD / 32), dim3(32, 8), 0, stream>>>(w1, wsc, DD, DFFN);
        gemm_k<2><<<16 * 32, 256, 0, stream>>>(xb, DD, wsc, DD, g, DFFN, b1, 16, DD);
        convT_k<<<dim3(DD / 32, DFFN / 32), dim3(32, 8), 0, stream>>>(w2, wsc, DFFN, DD);
        gemm_k<3><<<16 * 8, 256, 0, stream>>>(g, DFFN, wsc, DFFN, x, DD, b2, 16, DFFN);
    }

    // ---- loss ----
    gather_xl_k<<<1024, 256, 0, stream>>>(x, xl);
    gemm_k<1><<<8 * 250, 256, 0, stream>>>(xl, DD, tembb, DD, logits, VV, nullptr, 8, DD);
    loss_row_k<<<1022, 256, 0, stream>>>(logits, tok, rowloss);
    loss_final_k<<<1, 256, 0, stream>>>(rowloss, (float*)d_out);
}